// Round 2
// baseline (261.599 us; speedup 1.0000x reference)
//
#include <hip/hip_runtime.h>

// Problem constants
constexpr int NN  = 50000;   // nodes
constexpr int NE  = 400000;  // edges
constexpr int F0  = 128;     // input features
constexpr int F1  = 512;     // hidden features
constexpr int F2  = 250;     // output features
constexpr int MT64 = 782;    // M tiles of 64 (782*64 = 50048)
constexpr int SLOT = 64;     // fixed-capacity CSR stride (Poisson(8): P(deg>64)~1e-40)

typedef short  short8 __attribute__((ext_vector_type(8)));
typedef float  f32x4  __attribute__((ext_vector_type(4)));
typedef float  f32x2  __attribute__((ext_vector_type(2)));

__device__ inline unsigned short f2bf(float f) {
    union { float f; unsigned u; } v; v.f = f;
    unsigned u = v.u;
    return (unsigned short)((u + 0x7FFFu + ((u >> 16) & 1u)) >> 16);   // RNE
}
__device__ inline float bf2f(unsigned short h) {
    union { unsigned u; float f; } v; v.u = ((unsigned)h) << 16;
    return v.f;
}
__device__ inline float bflo(unsigned u) {
    union { unsigned u; float f; } v; v.u = u << 16; return v.f;
}
__device__ inline float bfhi(unsigned u) {
    union { unsigned u; float f; } v; v.u = u & 0xFFFF0000u; return v.f;
}

// ========= CSR build: fused hist+bucket, COLUMN-MAJOR ushort slots =========
// slot[j*NN + n] = j-th in-neighbor of node n. ushort ok: NN < 65536.
// Column-major keeps the per-j working set dense (100 KB per j-slice) so the
// per-XCD chunk passes in the gathers re-read adjacency from L2, not HBM.
__global__ void k_build(const int4* __restrict__ src4, const int4* __restrict__ dst4,
                        int* __restrict__ cnt, unsigned short* __restrict__ slot) {
    int t = blockIdx.x * 256 + threadIdx.x;        // NE/4
    if (t >= NE / 4) return;
    int4 s = src4[t];
    int4 d = dst4[t];
    int p;
    p = atomicAdd(&cnt[d.x], 1); if (p < SLOT) slot[(size_t)p * NN + d.x] = (unsigned short)s.x;
    p = atomicAdd(&cnt[d.y], 1); if (p < SLOT) slot[(size_t)p * NN + d.y] = (unsigned short)s.y;
    p = atomicAdd(&cnt[d.z], 1); if (p < SLOT) slot[(size_t)p * NN + d.z] = (unsigned short)s.z;
    p = atomicAdd(&cnt[d.w], 1); if (p < SLOT) slot[(size_t)p * NN + d.w] = (unsigned short)s.w;
}

// ========= fused prep: xs = bf16(rsqrt(cnt+1)*x) in CHUNKED layout, W1t, W2t ==
// xs layout: [4 chunks][NN][32 ushorts] — 32-col slices contiguous (3.2 MB each)
// so one slice fits a 4 MB per-XCD L2 and 128B lines never straddle chunks.
__global__ __launch_bounds__(256) void k_prep(
        const float4* __restrict__ x4, const int* __restrict__ cnt,
        ushort4* __restrict__ xs,
        const float* __restrict__ W1, unsigned short* __restrict__ w1t,
        const float* __restrict__ W2, unsigned short* __restrict__ w2t) {
    int b = blockIdx.x;
    if (b < 6250) {                                // NN*32 = 1,600,000 float4s
        int t = b * 256 + threadIdx.x;
        int n = t >> 5, p = t & 31;                // p: ushort4 index within row
        float dn = rsqrtf((float)cnt[n] + 1.0f);
        float4 v = x4[t];
        ushort4 o;
        o.x = f2bf(dn * v.x); o.y = f2bf(dn * v.y);
        o.z = f2bf(dn * v.z); o.w = f2bf(dn * v.w);
        int ch = p >> 3, pp = p & 7;               // chunk (32 cols = 8 ushort4)
        xs[((size_t)ch * NN + n) * 8 + pp] = o;
    } else if (b < 6250 + 256) {                   // W1 [128,512] -> [512,128]
        int t = (b - 6250) * 256 + threadIdx.x;
        int n = t >> 7, k = t & 127;
        w1t[t] = f2bf(W1[k * F1 + n]);
    } else {                                       // W2 [512,250] -> [256,512], pad
        int t = (b - 6506) * 256 + threadIdx.x;
        int n = t >> 9, k = t & 511;
        w2t[t] = (n < F2) ? f2bf(W2[k * F2 + n]) : (unsigned short)0;
    }
}

// ========= gather1: agg1 = bf16( dn * ( xs[n] + sum xs[s] ) ) ============
// XCD-pinned column slicing: chunk = (blockIdx%8)>>1 (XCD pair per 3.2 MB
// slice). 16-lane groups, 4 nodes/wave, uint loads (64 B per row-slice).
__global__ __launch_bounds__(256) void k_gather1(
        const unsigned int* __restrict__ xs,       // [4][NN][16] uints
        const unsigned short* __restrict__ slot,   // [SLOT][NN]
        const int* __restrict__ cnt, unsigned int* __restrict__ agg) {
    const int r  = blockIdx.x & 7;                 // XCD residue
    const int q  = blockIdx.x >> 3;
    const int ch = r >> 1;                         // chunk -> XCD pair {2c,2c+1}
    const int nb = q * 2 + (r & 1);                // node-block within chunk
    const int ln = threadIdx.x & 63;
    const int g  = ln >> 4, l = ln & 15;
    const int n  = nb * 16 + (threadIdx.x >> 6) * 4 + g;
    if (n >= NN) return;
    int deg = cnt[n]; if (deg > SLOT) deg = SLOT;
    float dn = rsqrtf((float)deg + 1.0f);
    const unsigned int* base = xs + (size_t)ch * NN * 16;
    const unsigned short* sl = slot + n;
    unsigned a = base[(size_t)n * 16 + l];
    float s0 = bflo(a), s1 = bfhi(a);
    int j = 0;
    for (; j + 8 <= deg; j += 8) {
        int i0 = sl[(j + 0) * NN], i1 = sl[(j + 1) * NN];
        int i2 = sl[(j + 2) * NN], i3 = sl[(j + 3) * NN];
        int i4 = sl[(j + 4) * NN], i5 = sl[(j + 5) * NN];
        int i6 = sl[(j + 6) * NN], i7 = sl[(j + 7) * NN];
        unsigned v0 = base[(size_t)i0 * 16 + l];
        unsigned v1 = base[(size_t)i1 * 16 + l];
        unsigned v2 = base[(size_t)i2 * 16 + l];
        unsigned v3 = base[(size_t)i3 * 16 + l];
        unsigned v4 = base[(size_t)i4 * 16 + l];
        unsigned v5 = base[(size_t)i5 * 16 + l];
        unsigned v6 = base[(size_t)i6 * 16 + l];
        unsigned v7 = base[(size_t)i7 * 16 + l];
        s0 += bflo(v0) + bflo(v1) + bflo(v2) + bflo(v3)
            + bflo(v4) + bflo(v5) + bflo(v6) + bflo(v7);
        s1 += bfhi(v0) + bfhi(v1) + bfhi(v2) + bfhi(v3)
            + bfhi(v4) + bfhi(v5) + bfhi(v6) + bfhi(v7);
    }
    for (; j + 4 <= deg; j += 4) {
        int i0 = sl[(j + 0) * NN], i1 = sl[(j + 1) * NN];
        int i2 = sl[(j + 2) * NN], i3 = sl[(j + 3) * NN];
        unsigned v0 = base[(size_t)i0 * 16 + l];
        unsigned v1 = base[(size_t)i1 * 16 + l];
        unsigned v2 = base[(size_t)i2 * 16 + l];
        unsigned v3 = base[(size_t)i3 * 16 + l];
        s0 += bflo(v0) + bflo(v1) + bflo(v2) + bflo(v3);
        s1 += bfhi(v0) + bfhi(v1) + bfhi(v2) + bfhi(v3);
    }
    for (; j < deg; ++j) {
        unsigned v = base[(size_t)sl[j * NN] * 16 + l];
        s0 += bflo(v); s1 += bfhi(v);
    }
    unsigned o = (unsigned)f2bf(dn * s0) | ((unsigned)f2bf(dn * s1) << 16);
    __builtin_nontemporal_store(o, &agg[((size_t)ch * NN + n) * 16 + l]);
}

// ========= gemm1: single-shot K=128 bf16 MFMA GEMM (+bias+relu) =========
// C[M,512] = A[M,128] * Bt[512,128]^T. A is in chunked [4][NN][32] layout.
__global__ __launch_bounds__(256) void k_gemm1(
        const unsigned short* __restrict__ A,
        const unsigned short* __restrict__ Bt,
        unsigned short* __restrict__ C,
        const float* __restrict__ bias, int M)
{
    __shared__ unsigned short As[64 * 128];    // 16 KB
    __shared__ unsigned short Bs[128 * 128];   // 32 KB

    const int tid = threadIdx.x;
    const int wv = tid >> 6, ln = tid & 63;
    const int m0 = blockIdx.y * 64, n0 = blockIdx.x * 128;
    const int wy = wv >> 1, wx = wv & 1;
    const int lane15 = ln & 15, quad = ln >> 4;

#pragma unroll
    for (int i = 0; i < 4; ++i) {              // A: 1024 chunks
        int c = i * 256 + tid;
        int m = c >> 4, q = c & 15;
        int gq = q ^ (m & 15);
        int arow = m0 + m; if (arow > M - 1) arow = M - 1;
        // chunked A: ushort offset = (chunk*NN + row)*32 + (gq&3)*8
        const unsigned short* asrc =
            A + ((size_t)(gq >> 2) * NN + arow) * 32 + (gq & 3) * 8;
        __builtin_amdgcn_global_load_lds(
            (const __attribute__((address_space(1))) void*)asrc,
            (__attribute__((address_space(3))) void*)(As + (i * 4 + wv) * 512), 16, 0, 0);
    }
#pragma unroll
    for (int i = 0; i < 8; ++i) {              // B: 2048 chunks
        int c = i * 256 + tid;
        int n = c >> 4, q = c & 15;
        int gq = q ^ (n & 15);
        __builtin_amdgcn_global_load_lds(
            (const __attribute__((address_space(1))) void*)(Bt + (size_t)(n0 + n) * 128 + gq * 8),
            (__attribute__((address_space(3))) void*)(Bs + (i * 4 + wv) * 512), 16, 0, 0);
    }

    f32x4 acc[2][4];
#pragma unroll
    for (int fy = 0; fy < 2; ++fy)
#pragma unroll
        for (int fx = 0; fx < 4; ++fx)
            acc[fy][fx] = (f32x4)0.0f;

    __syncthreads();                             // the only barrier

#pragma unroll
    for (int kk = 0; kk < 4; ++kk) {             // K = 4 x 32
        short8 af[2], bf[4];
#pragma unroll
        for (int f = 0; f < 2; ++f) {
            int mA = wy * 32 + f * 16 + lane15;
            int sA = (kk * 4 + quad) ^ (mA & 15);
            af[f] = *(const short8*)(As + mA * 128 + sA * 8);
        }
#pragma unroll
        for (int f = 0; f < 4; ++f) {
            int nB = wx * 64 + f * 16 + lane15;
            int sB = (kk * 4 + quad) ^ (nB & 15);
            bf[f] = *(const short8*)(Bs + nB * 128 + sB * 8);
        }
#pragma unroll
        for (int fy = 0; fy < 2; ++fy)
#pragma unroll
            for (int fx = 0; fx < 4; ++fx)
                acc[fy][fx] = __builtin_amdgcn_mfma_f32_16x16x32_bf16(
                    af[fy], bf[fx], acc[fy][fx], 0, 0, 0);
    }

#pragma unroll
    for (int fy = 0; fy < 2; ++fy) {
        int rowb = m0 + wy * 32 + fy * 16 + quad * 4;
#pragma unroll
        for (int fx = 0; fx < 4; ++fx) {
            int col = n0 + wx * 64 + fx * 16 + lane15;
            float bia = bias[col];
            f32x4 v = acc[fy][fx];
#pragma unroll
            for (int r = 0; r < 4; ++r) {
                int row = rowb + r;
                if (row < M)
                    C[(size_t)row * F1 + col] = f2bf(fmaxf(v[r] + bia, 0.0f));
            }
        }
    }
}

// ========= gemm2: 64x256 (full-N) K=512 dbuf bf16 MFMA GEMM, rowscale =========
// Output C (t2s) written in chunked [8][NN][32] layout for the sliced gather2.
__global__ __launch_bounds__(256) void k_gemm2(
        const unsigned short* __restrict__ A,    // h1 [M,512]
        const unsigned short* __restrict__ Bt,   // w2t [256,512]
        unsigned short* __restrict__ C,          // t2s [8][NN][32]
        const int* __restrict__ cnt, int M)
{
    __shared__ unsigned short As[2][64 * 32];    // 2 x 4 KB
    __shared__ unsigned short Bs[2][256 * 32];   // 2 x 16 KB

    const int tid = threadIdx.x;
    const int wv = tid >> 6, ln = tid & 63;
    const int m0 = blockIdx.x * 64;
    const int wy = wv >> 1, wx = wv & 1;         // 2x2 waves: 32 rows x 128 cols each
    const int lane15 = ln & 15, quad = ln >> 4;

    // A staging: 256 chunks (64 rows x 4 slots), 1 per thread
    const int mA_ = tid >> 2, qA = tid & 3;
    const int gqA = qA ^ ((mA_ >> 1) & 3);
    int arow = m0 + mA_; if (arow > M - 1) arow = M - 1;
    const unsigned short* agp = A + (size_t)arow * F1 + gqA * 8;
    const int aofs = wv * 512;

    // B staging: 1024 chunks (256 rows x 4 slots), 4 per thread
    const unsigned short* bgp[4];
    int bofs[4];
#pragma unroll
    for (int i = 0; i < 4; ++i) {
        int c = (i * 4 + wv) * 64 + ln;
        int n = c >> 2, q = c & 3;
        int gq = q ^ ((n >> 1) & 3);
        bgp[i] = Bt + (size_t)n * F1 + gq * 8;
        bofs[i] = (i * 4 + wv) * 512;
    }

    f32x4 acc[2][8];
#pragma unroll
    for (int fy = 0; fy < 2; ++fy)
#pragma unroll
        for (int fx = 0; fx < 8; ++fx)
            acc[fy][fx] = (f32x4)0.0f;

    const int NK = F1 / 32;                      // 16

    __builtin_amdgcn_global_load_lds(
        (const __attribute__((address_space(1))) void*)agp,
        (__attribute__((address_space(3))) void*)(&As[0][0] + aofs), 16, 0, 0);
#pragma unroll
    for (int i = 0; i < 4; ++i)
        __builtin_amdgcn_global_load_lds(
            (const __attribute__((address_space(1))) void*)bgp[i],
            (__attribute__((address_space(3))) void*)(&Bs[0][0] + bofs[i]), 16, 0, 0);

    for (int ks = 0; ks < NK; ++ks) {
        __syncthreads();
        if (ks + 1 < NK) {
            int ko = (ks + 1) << 5;
            int nb = (ks + 1) & 1;
            __builtin_amdgcn_global_load_lds(
                (const __attribute__((address_space(1))) void*)(agp + ko),
                (__attribute__((address_space(3))) void*)(&As[nb][0] + aofs), 16, 0, 0);
#pragma unroll
            for (int i = 0; i < 4; ++i)
                __builtin_amdgcn_global_load_lds(
                    (const __attribute__((address_space(1))) void*)(bgp[i] + ko),
                    (__attribute__((address_space(3))) void*)(&Bs[nb][0] + bofs[i]), 16, 0, 0);
        }
        const int b = ks & 1;
        short8 af[2], bf[8];
#pragma unroll
        for (int f = 0; f < 2; ++f) {
            int mA = wy * 32 + f * 16 + lane15;
            int sA = quad ^ ((mA >> 1) & 3);
            af[f] = *(const short8*)(&As[b][0] + mA * 32 + sA * 8);
        }
#pragma unroll
        for (int f = 0; f < 8; ++f) {
            int nB = wx * 128 + f * 16 + lane15;
            int sB = quad ^ ((nB >> 1) & 3);
            bf[f] = *(const short8*)(&Bs[b][0] + nB * 32 + sB * 8);
        }
#pragma unroll
        for (int fy = 0; fy < 2; ++fy)
#pragma unroll
            for (int fx = 0; fx < 8; ++fx)
                acc[fy][fx] = __builtin_amdgcn_mfma_f32_16x16x32_bf16(
                    af[fy], bf[fx], acc[fy][fx], 0, 0, 0);
    }

#pragma unroll
    for (int fy = 0; fy < 2; ++fy) {
        int rowb = m0 + wy * 32 + fy * 16 + quad * 4;
        float rs[4];
#pragma unroll
        for (int r = 0; r < 4; ++r) {
            int row = rowb + r; if (row > M - 1) row = M - 1;
            rs[r] = rsqrtf((float)cnt[row] + 1.0f);
        }
#pragma unroll
        for (int fx = 0; fx < 8; ++fx) {
            int col = wx * 128 + fx * 16 + lane15;
            int chv = col >> 5, c5 = col & 31;   // chunked C layout
            f32x4 v = acc[fy][fx];
#pragma unroll
            for (int r = 0; r < 4; ++r) {
                int row = rowb + r;
                if (row < M)
                    C[((size_t)chv * NN + row) * 32 + c5] = f2bf(v[r] * rs[r]);
            }
        }
    }
}

// ========= gather2: out[n] = relu( dn*( t2s[n] + sum t2s[s] ) + b2 ) =========
// XCD-pinned: chunk = blockIdx%8 owns one 3.2 MB slice -> L2-resident gather.
// 16-lane groups, 4 nodes/wave; nontemporal f32x2 stores protect the slice.
__global__ __launch_bounds__(256) void k_gather2(
        const unsigned int* __restrict__ t2u,      // [8][NN][16] uints
        const unsigned short* __restrict__ slot,   // [SLOT][NN]
        const int* __restrict__ cnt, const float* __restrict__ b2,
        float* __restrict__ out) {
    const int r = blockIdx.x & 7;                  // chunk == XCD residue
    const int q = blockIdx.x >> 3;                 // node-block, < 3125
    const int ln = threadIdx.x & 63;
    const int g = ln >> 4, l = ln & 15;
    const int n = q * 16 + (threadIdx.x >> 6) * 4 + g;   // < 50000 exactly
    int deg = cnt[n]; if (deg > SLOT) deg = SLOT;
    float dn = rsqrtf((float)deg + 1.0f);
    const unsigned int* base = t2u + (size_t)r * NN * 16;
    const unsigned short* sl = slot + n;
    unsigned a = base[(size_t)n * 16 + l];
    float s0 = bflo(a), s1 = bfhi(a);
    int j = 0;
    for (; j + 8 <= deg; j += 8) {
        int i0 = sl[(j + 0) * NN], i1 = sl[(j + 1) * NN];
        int i2 = sl[(j + 2) * NN], i3 = sl[(j + 3) * NN];
        int i4 = sl[(j + 4) * NN], i5 = sl[(j + 5) * NN];
        int i6 = sl[(j + 6) * NN], i7 = sl[(j + 7) * NN];
        unsigned v0 = base[(size_t)i0 * 16 + l];
        unsigned v1 = base[(size_t)i1 * 16 + l];
        unsigned v2 = base[(size_t)i2 * 16 + l];
        unsigned v3 = base[(size_t)i3 * 16 + l];
        unsigned v4 = base[(size_t)i4 * 16 + l];
        unsigned v5 = base[(size_t)i5 * 16 + l];
        unsigned v6 = base[(size_t)i6 * 16 + l];
        unsigned v7 = base[(size_t)i7 * 16 + l];
        s0 += bflo(v0) + bflo(v1) + bflo(v2) + bflo(v3)
            + bflo(v4) + bflo(v5) + bflo(v6) + bflo(v7);
        s1 += bfhi(v0) + bfhi(v1) + bfhi(v2) + bfhi(v3)
            + bfhi(v4) + bfhi(v5) + bfhi(v6) + bfhi(v7);
    }
    for (; j + 4 <= deg; j += 4) {
        int i0 = sl[(j + 0) * NN], i1 = sl[(j + 1) * NN];
        int i2 = sl[(j + 2) * NN], i3 = sl[(j + 3) * NN];
        unsigned v0 = base[(size_t)i0 * 16 + l];
        unsigned v1 = base[(size_t)i1 * 16 + l];
        unsigned v2 = base[(size_t)i2 * 16 + l];
        unsigned v3 = base[(size_t)i3 * 16 + l];
        s0 += bflo(v0) + bflo(v1) + bflo(v2) + bflo(v3);
        s1 += bfhi(v0) + bfhi(v1) + bfhi(v2) + bfhi(v3);
    }
    for (; j < deg; ++j) {
        unsigned v = base[(size_t)sl[j * NN] * 16 + l];
        s0 += bflo(v); s1 += bfhi(v);
    }
    int f = r * 32 + l * 2;
    if (f < F2) {                                  // f even; f+1 <= 249 when f < 250
        f32x2 o2;
        o2.x = fmaxf(dn * s0 + b2[f],     0.f);
        o2.y = fmaxf(dn * s1 + b2[f + 1], 0.f);
        __builtin_nontemporal_store(o2, (f32x2*)(out + (size_t)n * F2 + f));
    }
}

extern "C" void kernel_launch(void* const* d_in, const int* in_sizes, int n_in,
                              void* d_out, int out_size, void* d_ws, size_t ws_size,
                              hipStream_t stream) {
    const float* x  = (const float*)d_in[0];
    const int*   ei = (const int*)d_in[1];     // [2, NE]: first NE = src, next NE = dst
    const float* W1 = (const float*)d_in[2];
    const float* b1 = (const float*)d_in[3];
    const float* W2 = (const float*)d_in[4];
    const float* b2 = (const float*)d_in[5];
    float* out = (float*)d_out;

    // workspace carve (256 B aligned)
    char* p = (char*)d_ws;
    auto carve = [&](size_t bytes) { char* r = p; p += (bytes + 255) & ~(size_t)255; return r; };
    int*            cnt  = (int*)carve(NN * 4);
    unsigned short* slot = (unsigned short*)carve((size_t)NN * SLOT * 2);  // [SLOT][NN]
    unsigned short* xs   = (unsigned short*)carve((size_t)NN * F0 * 2);    // [4][NN][32]
    unsigned short* agg1 = (unsigned short*)carve((size_t)NN * F0 * 2);    // [4][NN][32]
    unsigned short* h1   = (unsigned short*)carve((size_t)NN * F1 * 2);    // [M,512]
    unsigned short* t2s  = (unsigned short*)carve((size_t)NN * 256 * 2);   // [8][NN][32]
    unsigned short* w1t  = (unsigned short*)carve((size_t)F1 * F0 * 2);
    unsigned short* w2t  = (unsigned short*)carve((size_t)256 * F1 * 2);

    // 1) zero degree counters
    hipMemsetAsync(cnt, 0, NN * sizeof(int), stream);
    // 2) fused hist+bucket CSR build (column-major ushort slots)
    k_build<<<(NE / 4 + 255) / 256, 256, 0, stream>>>(
        (const int4*)ei, (const int4*)(ei + NE), cnt, slot);
    // 3) fused prep: xs = bf16(dinv*x) chunked, W1t, W2t
    k_prep<<<6250 + 256 + 512, 256, 0, stream>>>(
        (const float4*)x, cnt, (ushort4*)xs, W1, w1t, W2, w2t);
    // 4) layer 1 aggregate: 4 col-slices x XCD-pair pinned; 8*1563 blocks
    k_gather1<<<8 * 1563, 256, 0, stream>>>((const unsigned int*)xs, slot, cnt,
                                            (unsigned int*)agg1);
    // 5) layer 1 GEMM: single-shot K=128, one barrier (A chunked)
    k_gemm1<<<dim3(F1 / 128, MT64), 256, 0, stream>>>(agg1, w1t, h1, b1, NN);
    // 6) layer 2 GEMM: 64x256 full-N tile, rowscale -> t2s chunked
    k_gemm2<<<MT64, 256, 0, stream>>>(h1, w2t, t2s, cnt, NN);
    // 7) gather2 + bias + relu -> out: 8 col-slices x XCD pinned; 8*3125 blocks
    k_gather2<<<8 * 3125, 256, 0, stream>>>((const unsigned int*)t2s, slot, cnt, b2, out);
}

// Round 4
// 249.141 us; speedup vs baseline: 1.0500x; 1.0500x over previous
//
#include <hip/hip_runtime.h>

// Problem constants
constexpr int NN  = 50000;   // nodes
constexpr int NE  = 400000;  // edges
constexpr int F0  = 128;     // input features
constexpr int F1  = 512;     // hidden features
constexpr int F2  = 250;     // output features
constexpr int MT64 = 782;    // M tiles of 64 (782*64 = 50048)
constexpr int SLOT = 64;     // fixed-capacity CSR stride (Poisson(8): P(deg>64)~1e-40)

typedef short    short8 __attribute__((ext_vector_type(8)));
typedef float    f32x4  __attribute__((ext_vector_type(4)));
typedef float    f32x2  __attribute__((ext_vector_type(2)));
typedef unsigned u32x2  __attribute__((ext_vector_type(2)));

__device__ inline unsigned short f2bf(float f) {
    union { float f; unsigned u; } v; v.f = f;
    unsigned u = v.u;
    return (unsigned short)((u + 0x7FFFu + ((u >> 16) & 1u)) >> 16);   // RNE
}
__device__ inline float bflo(unsigned u) {
    union { unsigned u; float f; } v; v.u = u << 16; return v.f;
}
__device__ inline float bfhi(unsigned u) {
    union { unsigned u; float f; } v; v.u = u & 0xFFFF0000u; return v.f;
}

// ========= CSR build: fused hist+bucket, COLUMN-MAJOR ushort slots =========
// slot[j*NN + n] = j-th in-neighbor of node n. ushort ok: NN < 65536.
__global__ void k_build(const int4* __restrict__ src4, const int4* __restrict__ dst4,
                        int* __restrict__ cnt, unsigned short* __restrict__ slot) {
    int t = blockIdx.x * 256 + threadIdx.x;        // NE/4
    if (t >= NE / 4) return;
    int4 s = src4[t];
    int4 d = dst4[t];
    int p;
    p = atomicAdd(&cnt[d.x], 1); if (p < SLOT) slot[(size_t)p * NN + d.x] = (unsigned short)s.x;
    p = atomicAdd(&cnt[d.y], 1); if (p < SLOT) slot[(size_t)p * NN + d.y] = (unsigned short)s.y;
    p = atomicAdd(&cnt[d.z], 1); if (p < SLOT) slot[(size_t)p * NN + d.z] = (unsigned short)s.z;
    p = atomicAdd(&cnt[d.w], 1); if (p < SLOT) slot[(size_t)p * NN + d.w] = (unsigned short)s.w;
}

// ========= fused prep: xs = bf16(rsqrt(cnt+1)*x) in CHUNKED layout, W1t, W2t ==
// xs layout: [4 chunks][NN][32 ushorts] — 3.2 MB per 32-col slice (L2-fits).
__global__ __launch_bounds__(256) void k_prep(
        const float4* __restrict__ x4, const int* __restrict__ cnt,
        ushort4* __restrict__ xs,
        const float* __restrict__ W1, unsigned short* __restrict__ w1t,
        const float* __restrict__ W2, unsigned short* __restrict__ w2t) {
    int b = blockIdx.x;
    if (b < 6250) {                                // NN*32 = 1,600,000 float4s
        int t = b * 256 + threadIdx.x;
        int n = t >> 5, p = t & 31;                // p: ushort4 index within row
        float dn = rsqrtf((float)cnt[n] + 1.0f);
        float4 v = x4[t];
        ushort4 o;
        o.x = f2bf(dn * v.x); o.y = f2bf(dn * v.y);
        o.z = f2bf(dn * v.z); o.w = f2bf(dn * v.w);
        int ch = p >> 3, pp = p & 7;               // chunk (32 cols = 8 ushort4)
        xs[((size_t)ch * NN + n) * 8 + pp] = o;
    } else if (b < 6250 + 256) {                   // W1 [128,512] -> [512,128]
        int t = (b - 6250) * 256 + threadIdx.x;
        int n = t >> 7, k = t & 127;
        w1t[t] = f2bf(W1[k * F1 + n]);
    } else {                                       // W2 [512,250] -> [256,512], pad
        int t = (b - 6506) * 256 + threadIdx.x;
        int n = t >> 9, k = t & 511;
        w2t[t] = (n < F2) ? f2bf(W2[k * F2 + n]) : (unsigned short)0;
    }
}

// ========= gather1: agg1 = bf16( dn * ( xs[n] + sum xs[s] ) ) ============
// 8-lane groups x u32x2 (8 B/lane): one wave instr = 8 nodes x 64 B = 512 B.
// Chunk ch pinned to XCD pair via blockIdx%8; slice 3.2 MB -> L2-resident.
__global__ __launch_bounds__(256) void k_gather1(
        const u32x2* __restrict__ xs,              // [4][NN][8] u32x2
        const unsigned short* __restrict__ slot,   // [SLOT][NN]
        const int* __restrict__ cnt, u32x2* __restrict__ agg) {
    const int r  = blockIdx.x & 7;                 // XCD residue
    const int q  = blockIdx.x >> 3;                // < 782
    const int ch = r >> 1;                         // chunk -> XCD pair {2c,2c+1}
    const int nb = q * 2 + (r & 1);                // node-block within chunk, <1564
    const int ln = threadIdx.x & 63;
    const int g  = ln >> 3, l = ln & 7;
    const int n  = nb * 32 + (threadIdx.x >> 6) * 8 + g;
    if (n >= NN) return;
    int deg = cnt[n]; if (deg > SLOT) deg = SLOT;
    float dn = rsqrtf((float)deg + 1.0f);
    const u32x2* base = xs + (size_t)ch * NN * 8;
    const unsigned short* sl = slot + n;
    u32x2 a = base[(size_t)n * 8 + l];
    float s0 = bflo(a.x), s1 = bfhi(a.x), s2 = bflo(a.y), s3 = bfhi(a.y);
    int j = 0;
    for (; j + 8 <= deg; j += 8) {
        int i0 = sl[(j + 0) * NN], i1 = sl[(j + 1) * NN];
        int i2 = sl[(j + 2) * NN], i3 = sl[(j + 3) * NN];
        int i4 = sl[(j + 4) * NN], i5 = sl[(j + 5) * NN];
        int i6 = sl[(j + 6) * NN], i7 = sl[(j + 7) * NN];
        u32x2 v0 = base[(size_t)i0 * 8 + l];
        u32x2 v1 = base[(size_t)i1 * 8 + l];
        u32x2 v2 = base[(size_t)i2 * 8 + l];
        u32x2 v3 = base[(size_t)i3 * 8 + l];
        u32x2 v4 = base[(size_t)i4 * 8 + l];
        u32x2 v5 = base[(size_t)i5 * 8 + l];
        u32x2 v6 = base[(size_t)i6 * 8 + l];
        u32x2 v7 = base[(size_t)i7 * 8 + l];
        s0 += bflo(v0.x) + bflo(v1.x) + bflo(v2.x) + bflo(v3.x)
            + bflo(v4.x) + bflo(v5.x) + bflo(v6.x) + bflo(v7.x);
        s1 += bfhi(v0.x) + bfhi(v1.x) + bfhi(v2.x) + bfhi(v3.x)
            + bfhi(v4.x) + bfhi(v5.x) + bfhi(v6.x) + bfhi(v7.x);
        s2 += bflo(v0.y) + bflo(v1.y) + bflo(v2.y) + bflo(v3.y)
            + bflo(v4.y) + bflo(v5.y) + bflo(v6.y) + bflo(v7.y);
        s3 += bfhi(v0.y) + bfhi(v1.y) + bfhi(v2.y) + bfhi(v3.y)
            + bfhi(v4.y) + bfhi(v5.y) + bfhi(v6.y) + bfhi(v7.y);
    }
    for (; j + 4 <= deg; j += 4) {
        int i0 = sl[(j + 0) * NN], i1 = sl[(j + 1) * NN];
        int i2 = sl[(j + 2) * NN], i3 = sl[(j + 3) * NN];
        u32x2 v0 = base[(size_t)i0 * 8 + l];
        u32x2 v1 = base[(size_t)i1 * 8 + l];
        u32x2 v2 = base[(size_t)i2 * 8 + l];
        u32x2 v3 = base[(size_t)i3 * 8 + l];
        s0 += bflo(v0.x) + bflo(v1.x) + bflo(v2.x) + bflo(v3.x);
        s1 += bfhi(v0.x) + bfhi(v1.x) + bfhi(v2.x) + bfhi(v3.x);
        s2 += bflo(v0.y) + bflo(v1.y) + bflo(v2.y) + bflo(v3.y);
        s3 += bfhi(v0.y) + bfhi(v1.y) + bfhi(v2.y) + bfhi(v3.y);
    }
    for (; j < deg; ++j) {
        u32x2 v = base[(size_t)sl[j * NN] * 8 + l];
        s0 += bflo(v.x); s1 += bfhi(v.x); s2 += bflo(v.y); s3 += bfhi(v.y);
    }
    u32x2 o;
    o.x = (unsigned)f2bf(dn * s0) | ((unsigned)f2bf(dn * s1) << 16);
    o.y = (unsigned)f2bf(dn * s2) | ((unsigned)f2bf(dn * s3) << 16);
    __builtin_nontemporal_store(o, &agg[((size_t)ch * NN + n) * 8 + l]);
}

// ========= gemm1: single-shot K=128 bf16 MFMA GEMM (+bias+relu) =========
// C[M,512] = A[M,128] * Bt[512,128]^T. A is in chunked [4][NN][32] layout.
__global__ __launch_bounds__(256) void k_gemm1(
        const unsigned short* __restrict__ A,
        const unsigned short* __restrict__ Bt,
        unsigned short* __restrict__ C,
        const float* __restrict__ bias, int M)
{
    __shared__ unsigned short As[64 * 128];    // 16 KB
    __shared__ unsigned short Bs[128 * 128];   // 32 KB

    const int tid = threadIdx.x;
    const int wv = tid >> 6, ln = tid & 63;
    const int m0 = blockIdx.y * 64, n0 = blockIdx.x * 128;
    const int wy = wv >> 1, wx = wv & 1;
    const int lane15 = ln & 15, quad = ln >> 4;

#pragma unroll
    for (int i = 0; i < 4; ++i) {              // A: 1024 chunks
        int c = i * 256 + tid;
        int m = c >> 4, q = c & 15;
        int gq = q ^ (m & 15);
        int arow = m0 + m; if (arow > M - 1) arow = M - 1;
        const unsigned short* asrc =
            A + ((size_t)(gq >> 2) * NN + arow) * 32 + (gq & 3) * 8;
        __builtin_amdgcn_global_load_lds(
            (const __attribute__((address_space(1))) void*)asrc,
            (__attribute__((address_space(3))) void*)(As + (i * 4 + wv) * 512), 16, 0, 0);
    }
#pragma unroll
    for (int i = 0; i < 8; ++i) {              // B: 2048 chunks
        int c = i * 256 + tid;
        int n = c >> 4, q = c & 15;
        int gq = q ^ (n & 15);
        __builtin_amdgcn_global_load_lds(
            (const __attribute__((address_space(1))) void*)(Bt + (size_t)(n0 + n) * 128 + gq * 8),
            (__attribute__((address_space(3))) void*)(Bs + (i * 4 + wv) * 512), 16, 0, 0);
    }

    f32x4 acc[2][4];
#pragma unroll
    for (int fy = 0; fy < 2; ++fy)
#pragma unroll
        for (int fx = 0; fx < 4; ++fx)
            acc[fy][fx] = (f32x4)0.0f;

    __syncthreads();                             // the only barrier

#pragma unroll
    for (int kk = 0; kk < 4; ++kk) {             // K = 4 x 32
        short8 af[2], bf[4];
#pragma unroll
        for (int f = 0; f < 2; ++f) {
            int mA = wy * 32 + f * 16 + lane15;
            int sA = (kk * 4 + quad) ^ (mA & 15);
            af[f] = *(const short8*)(As + mA * 128 + sA * 8);
        }
#pragma unroll
        for (int f = 0; f < 4; ++f) {
            int nB = wx * 64 + f * 16 + lane15;
            int sB = (kk * 4 + quad) ^ (nB & 15);
            bf[f] = *(const short8*)(Bs + nB * 128 + sB * 8);
        }
#pragma unroll
        for (int fy = 0; fy < 2; ++fy)
#pragma unroll
            for (int fx = 0; fx < 4; ++fx)
                acc[fy][fx] = __builtin_amdgcn_mfma_f32_16x16x32_bf16(
                    af[fy], bf[fx], acc[fy][fx], 0, 0, 0);
    }

#pragma unroll
    for (int fy = 0; fy < 2; ++fy) {
        int rowb = m0 + wy * 32 + fy * 16 + quad * 4;
#pragma unroll
        for (int fx = 0; fx < 4; ++fx) {
            int col = n0 + wx * 64 + fx * 16 + lane15;
            float bia = bias[col];
            f32x4 v = acc[fy][fx];
#pragma unroll
            for (int r = 0; r < 4; ++r) {
                int row = rowb + r;
                if (row < M)
                    C[(size_t)row * F1 + col] = f2bf(fmaxf(v[r] + bia, 0.0f));
            }
        }
    }
}

// ========= gemm2: 64x256 (full-N) K=512 dbuf bf16 MFMA GEMM, rowscale =========
// Output C (t2s) written in chunked [8][NN][32] layout for the sliced gather2.
__global__ __launch_bounds__(256) void k_gemm2(
        const unsigned short* __restrict__ A,    // h1 [M,512]
        const unsigned short* __restrict__ Bt,   // w2t [256,512]
        unsigned short* __restrict__ C,          // t2s [8][NN][32]
        const int* __restrict__ cnt, int M)
{
    __shared__ unsigned short As[2][64 * 32];    // 2 x 4 KB
    __shared__ unsigned short Bs[2][256 * 32];   // 2 x 16 KB

    const int tid = threadIdx.x;
    const int wv = tid >> 6, ln = tid & 63;
    const int m0 = blockIdx.x * 64;
    const int wy = wv >> 1, wx = wv & 1;         // 2x2 waves: 32 rows x 128 cols each
    const int lane15 = ln & 15, quad = ln >> 4;

    // A staging: 256 chunks (64 rows x 4 slots), 1 per thread
    const int mA_ = tid >> 2, qA = tid & 3;
    const int gqA = qA ^ ((mA_ >> 1) & 3);
    int arow = m0 + mA_; if (arow > M - 1) arow = M - 1;
    const unsigned short* agp = A + (size_t)arow * F1 + gqA * 8;
    const int aofs = wv * 512;

    // B staging: 1024 chunks (256 rows x 4 slots), 4 per thread
    const unsigned short* bgp[4];
    int bofs[4];
#pragma unroll
    for (int i = 0; i < 4; ++i) {
        int c = (i * 4 + wv) * 64 + ln;
        int n = c >> 2, q = c & 3;
        int gq = q ^ ((n >> 1) & 3);
        bgp[i] = Bt + (size_t)n * F1 + gq * 8;
        bofs[i] = (i * 4 + wv) * 512;
    }

    f32x4 acc[2][8];
#pragma unroll
    for (int fy = 0; fy < 2; ++fy)
#pragma unroll
        for (int fx = 0; fx < 8; ++fx)
            acc[fy][fx] = (f32x4)0.0f;

    const int NK = F1 / 32;                      // 16

    __builtin_amdgcn_global_load_lds(
        (const __attribute__((address_space(1))) void*)agp,
        (__attribute__((address_space(3))) void*)(&As[0][0] + aofs), 16, 0, 0);
#pragma unroll
    for (int i = 0; i < 4; ++i)
        __builtin_amdgcn_global_load_lds(
            (const __attribute__((address_space(1))) void*)bgp[i],
            (__attribute__((address_space(3))) void*)(&Bs[0][0] + bofs[i]), 16, 0, 0);

    for (int ks = 0; ks < NK; ++ks) {
        __syncthreads();
        if (ks + 1 < NK) {
            int ko = (ks + 1) << 5;
            int nb = (ks + 1) & 1;
            __builtin_amdgcn_global_load_lds(
                (const __attribute__((address_space(1))) void*)(agp + ko),
                (__attribute__((address_space(3))) void*)(&As[nb][0] + aofs), 16, 0, 0);
#pragma unroll
            for (int i = 0; i < 4; ++i)
                __builtin_amdgcn_global_load_lds(
                    (const __attribute__((address_space(1))) void*)(bgp[i] + ko),
                    (__attribute__((address_space(3))) void*)(&Bs[nb][0] + bofs[i]), 16, 0, 0);
        }
        const int b = ks & 1;
        short8 af[2], bf[8];
#pragma unroll
        for (int f = 0; f < 2; ++f) {
            int mA = wy * 32 + f * 16 + lane15;
            int sA = quad ^ ((mA >> 1) & 3);
            af[f] = *(const short8*)(&As[b][0] + mA * 32 + sA * 8);
        }
#pragma unroll
        for (int f = 0; f < 8; ++f) {
            int nB = wx * 128 + f * 16 + lane15;
            int sB = quad ^ ((nB >> 1) & 3);
            bf[f] = *(const short8*)(&Bs[b][0] + nB * 32 + sB * 8);
        }
#pragma unroll
        for (int fy = 0; fy < 2; ++fy)
#pragma unroll
            for (int fx = 0; fx < 8; ++fx)
                acc[fy][fx] = __builtin_amdgcn_mfma_f32_16x16x32_bf16(
                    af[fy], bf[fx], acc[fy][fx], 0, 0, 0);
    }

#pragma unroll
    for (int fy = 0; fy < 2; ++fy) {
        int rowb = m0 + wy * 32 + fy * 16 + quad * 4;
        float rs[4];
#pragma unroll
        for (int r = 0; r < 4; ++r) {
            int row = rowb + r; if (row > M - 1) row = M - 1;
            rs[r] = rsqrtf((float)cnt[row] + 1.0f);
        }
#pragma unroll
        for (int fx = 0; fx < 8; ++fx) {
            int col = wx * 128 + fx * 16 + lane15;
            int chv = col >> 5, c5 = col & 31;   // chunked C layout
            f32x4 v = acc[fy][fx];
#pragma unroll
            for (int r = 0; r < 4; ++r) {
                int row = rowb + r;
                if (row < M)
                    C[((size_t)chv * NN + row) * 32 + c5] = f2bf(v[r] * rs[r]);
            }
        }
    }
}

// ========= gather2: out[n] = relu( dn*( t2s[n] + sum t2s[s] ) + b2 ) =========
// 8-lane groups x u32x2: one wave instr = 8 nodes x 64 B = 512 B.
// Chunk r = blockIdx%8 pinned per-XCD; 3.2 MB slice L2-resident.
__global__ __launch_bounds__(256) void k_gather2(
        const u32x2* __restrict__ t2u,             // [8][NN][8] u32x2
        const unsigned short* __restrict__ slot,   // [SLOT][NN]
        const int* __restrict__ cnt, const float* __restrict__ b2,
        float* __restrict__ out) {
    const int r = blockIdx.x & 7;                  // chunk == XCD residue
    const int q = blockIdx.x >> 3;                 // node-block, < 1563
    const int ln = threadIdx.x & 63;
    const int g = ln >> 3, l = ln & 7;
    const int n = q * 32 + (threadIdx.x >> 6) * 8 + g;
    if (n >= NN) return;
    int deg = cnt[n]; if (deg > SLOT) deg = SLOT;
    float dn = rsqrtf((float)deg + 1.0f);
    const u32x2* base = t2u + (size_t)r * NN * 8;
    const unsigned short* sl = slot + n;
    u32x2 a = base[(size_t)n * 8 + l];
    float s0 = bflo(a.x), s1 = bfhi(a.x), s2 = bflo(a.y), s3 = bfhi(a.y);
    int j = 0;
    for (; j + 8 <= deg; j += 8) {
        int i0 = sl[(j + 0) * NN], i1 = sl[(j + 1) * NN];
        int i2 = sl[(j + 2) * NN], i3 = sl[(j + 3) * NN];
        int i4 = sl[(j + 4) * NN], i5 = sl[(j + 5) * NN];
        int i6 = sl[(j + 6) * NN], i7 = sl[(j + 7) * NN];
        u32x2 v0 = base[(size_t)i0 * 8 + l];
        u32x2 v1 = base[(size_t)i1 * 8 + l];
        u32x2 v2 = base[(size_t)i2 * 8 + l];
        u32x2 v3 = base[(size_t)i3 * 8 + l];
        u32x2 v4 = base[(size_t)i4 * 8 + l];
        u32x2 v5 = base[(size_t)i5 * 8 + l];
        u32x2 v6 = base[(size_t)i6 * 8 + l];
        u32x2 v7 = base[(size_t)i7 * 8 + l];
        s0 += bflo(v0.x) + bflo(v1.x) + bflo(v2.x) + bflo(v3.x)
            + bflo(v4.x) + bflo(v5.x) + bflo(v6.x) + bflo(v7.x);
        s1 += bfhi(v0.x) + bfhi(v1.x) + bfhi(v2.x) + bfhi(v3.x)
            + bfhi(v4.x) + bfhi(v5.x) + bfhi(v6.x) + bfhi(v7.x);
        s2 += bflo(v0.y) + bflo(v1.y) + bflo(v2.y) + bflo(v3.y)
            + bflo(v4.y) + bflo(v5.y) + bflo(v6.y) + bflo(v7.y);
        s3 += bfhi(v0.y) + bfhi(v1.y) + bfhi(v2.y) + bfhi(v3.y)
            + bfhi(v4.y) + bfhi(v5.y) + bfhi(v6.y) + bfhi(v7.y);
    }
    for (; j + 4 <= deg; j += 4) {
        int i0 = sl[(j + 0) * NN], i1 = sl[(j + 1) * NN];
        int i2 = sl[(j + 2) * NN], i3 = sl[(j + 3) * NN];
        u32x2 v0 = base[(size_t)i0 * 8 + l];
        u32x2 v1 = base[(size_t)i1 * 8 + l];
        u32x2 v2 = base[(size_t)i2 * 8 + l];
        u32x2 v3 = base[(size_t)i3 * 8 + l];
        s0 += bflo(v0.x) + bflo(v1.x) + bflo(v2.x) + bflo(v3.x);
        s1 += bfhi(v0.x) + bfhi(v1.x) + bfhi(v2.x) + bfhi(v3.x);
        s2 += bflo(v0.y) + bflo(v1.y) + bflo(v2.y) + bflo(v3.y);
        s3 += bfhi(v0.y) + bfhi(v1.y) + bfhi(v2.y) + bfhi(v3.y);
    }
    for (; j < deg; ++j) {
        u32x2 v = base[(size_t)sl[j * NN] * 8 + l];
        s0 += bflo(v.x); s1 += bfhi(v.x); s2 += bflo(v.y); s3 += bfhi(v.y);
    }
    int f = r * 32 + l * 4;
    float* o = out + (size_t)n * F2;
    if (f + 3 < F2) {
        f32x2 oa, ob;
        oa.x = fmaxf(dn * s0 + b2[f],     0.f);
        oa.y = fmaxf(dn * s1 + b2[f + 1], 0.f);
        ob.x = fmaxf(dn * s2 + b2[f + 2], 0.f);
        ob.y = fmaxf(dn * s3 + b2[f + 3], 0.f);
        __builtin_nontemporal_store(oa, (f32x2*)(o + f));
        __builtin_nontemporal_store(ob, (f32x2*)(o + f + 2));
    } else if (f < F2) {                           // tail: f = 248 only
        o[f] = fmaxf(dn * s0 + b2[f], 0.f);
        if (f + 1 < F2) o[f + 1] = fmaxf(dn * s1 + b2[f + 1], 0.f);
    }
}

extern "C" void kernel_launch(void* const* d_in, const int* in_sizes, int n_in,
                              void* d_out, int out_size, void* d_ws, size_t ws_size,
                              hipStream_t stream) {
    const float* x  = (const float*)d_in[0];
    const int*   ei = (const int*)d_in[1];     // [2, NE]: first NE = src, next NE = dst
    const float* W1 = (const float*)d_in[2];
    const float* b1 = (const float*)d_in[3];
    const float* W2 = (const float*)d_in[4];
    const float* b2 = (const float*)d_in[5];
    float* out = (float*)d_out;

    // workspace carve (256 B aligned)
    char* p = (char*)d_ws;
    auto carve = [&](size_t bytes) { char* r = p; p += (bytes + 255) & ~(size_t)255; return r; };
    int*            cnt  = (int*)carve(NN * 4);
    unsigned short* slot = (unsigned short*)carve((size_t)NN * SLOT * 2);  // [SLOT][NN]
    unsigned short* xs   = (unsigned short*)carve((size_t)NN * F0 * 2);    // [4][NN][32]
    unsigned short* agg1 = (unsigned short*)carve((size_t)NN * F0 * 2);    // [4][NN][32]
    unsigned short* h1   = (unsigned short*)carve((size_t)NN * F1 * 2);    // [M,512]
    unsigned short* t2s  = (unsigned short*)carve((size_t)NN * 256 * 2);   // [8][NN][32]
    unsigned short* w1t  = (unsigned short*)carve((size_t)F1 * F0 * 2);
    unsigned short* w2t  = (unsigned short*)carve((size_t)256 * F1 * 2);

    // 1) zero degree counters
    hipMemsetAsync(cnt, 0, NN * sizeof(int), stream);
    // 2) fused hist+bucket CSR build (column-major ushort slots)
    k_build<<<(NE / 4 + 255) / 256, 256, 0, stream>>>(
        (const int4*)ei, (const int4*)(ei + NE), cnt, slot);
    // 3) fused prep: xs = bf16(dinv*x) chunked, W1t, W2t
    k_prep<<<6250 + 256 + 512, 256, 0, stream>>>(
        (const float4*)x, cnt, (ushort4*)xs, W1, w1t, W2, w2t);
    // 4) layer 1 aggregate: 4 slices x XCD-pair pinned, 32 nodes/block
    k_gather1<<<8 * 782, 256, 0, stream>>>((const u32x2*)xs, slot, cnt,
                                           (u32x2*)agg1);
    // 5) layer 1 GEMM: single-shot K=128, one barrier (A chunked)
    k_gemm1<<<dim3(F1 / 128, MT64), 256, 0, stream>>>(agg1, w1t, h1, b1, NN);
    // 6) layer 2 GEMM: 64x256 full-N tile, rowscale -> t2s chunked
    k_gemm2<<<MT64, 256, 0, stream>>>(h1, w2t, t2s, cnt, NN);
    // 7) gather2 + bias + relu -> out: 8 slices x XCD pinned, 32 nodes/block
    k_gather2<<<8 * 1563, 256, 0, stream>>>((const u32x2*)t2s, slot, cnt, b2, out);
}

// Round 5
// 239.736 us; speedup vs baseline: 1.0912x; 1.0392x over previous
//
#include <hip/hip_runtime.h>

// Problem constants
constexpr int NN  = 50000;   // nodes
constexpr int NE  = 400000;  // edges
constexpr int F0  = 128;     // input features
constexpr int F1  = 512;     // hidden features
constexpr int F2  = 250;     // output features
constexpr int MT32 = 1563;   // M tiles of 32 (1563*32 = 50016)
constexpr int SLOT = 64;     // fixed-capacity CSR stride (Poisson(8): P(deg>64)~1e-40)

typedef short  short8 __attribute__((ext_vector_type(8)));
typedef float  f32x4  __attribute__((ext_vector_type(4)));

__device__ inline unsigned short f2bf(float f) {
    union { float f; unsigned u; } v; v.f = f;
    unsigned u = v.u;
    return (unsigned short)((u + 0x7FFFu + ((u >> 16) & 1u)) >> 16);   // RNE
}
__device__ inline float bf2f(unsigned short h) {
    union { unsigned u; float f; } v; v.u = ((unsigned)h) << 16;
    return v.f;
}
__device__ inline float bflo(unsigned u) {
    union { unsigned u; float f; } v; v.u = u << 16; return v.f;
}
__device__ inline float bfhi(unsigned u) {
    union { unsigned u; float f; } v; v.u = u & 0xFFFF0000u; return v.f;
}

// ========= CSR build: fused hist+bucket into fixed-stride slots (r0 form) ====
__global__ void k_build(const int4* __restrict__ src4, const int4* __restrict__ dst4,
                        int* __restrict__ cnt, int* __restrict__ slot) {
    int t = blockIdx.x * 256 + threadIdx.x;        // NE/4
    if (t >= NE / 4) return;
    int4 s = src4[t];
    int4 d = dst4[t];
    int p;
    p = atomicAdd(&cnt[d.x], 1); if (p < SLOT) slot[d.x * SLOT + p] = s.x;
    p = atomicAdd(&cnt[d.y], 1); if (p < SLOT) slot[d.y * SLOT + p] = s.y;
    p = atomicAdd(&cnt[d.z], 1); if (p < SLOT) slot[d.z * SLOT + p] = s.z;
    p = atomicAdd(&cnt[d.w], 1); if (p < SLOT) slot[d.w * SLOT + p] = s.w;
}

// ========= fused prep: xs = bf16(rsqrt(cnt+1)*x), W1t, W2t (r0 form) =========
__global__ __launch_bounds__(256) void k_prep(
        const float4* __restrict__ x4, const int* __restrict__ cnt,
        ushort4* __restrict__ xs,
        const float* __restrict__ W1, unsigned short* __restrict__ w1t,
        const float* __restrict__ W2, unsigned short* __restrict__ w2t) {
    int b = blockIdx.x;
    if (b < 6250) {                                // NN*32 = 1,600,000 float4s
        int t = b * 256 + threadIdx.x;
        float dn = rsqrtf((float)cnt[t >> 5] + 1.0f);
        float4 v = x4[t];
        ushort4 o;
        o.x = f2bf(dn * v.x); o.y = f2bf(dn * v.y);
        o.z = f2bf(dn * v.z); o.w = f2bf(dn * v.w);
        xs[t] = o;
    } else if (b < 6250 + 256) {                   // W1 [128,512] -> [512,128]
        int t = (b - 6250) * 256 + threadIdx.x;
        int n = t >> 7, k = t & 127;
        w1t[t] = f2bf(W1[k * F1 + n]);
    } else {                                       // W2 [512,250] -> [256,512], pad
        int t = (b - 6506) * 256 + threadIdx.x;
        int n = t >> 9, k = t & 511;
        w2t[t] = (n < F2) ? f2bf(W2[k * F2 + n]) : (unsigned short)0;
    }
}

// ========= gather1: agg1[n] = bf16( dn * ( xs[n] + sum xs[s] ) ) (r0 form) ===
__global__ __launch_bounds__(256) void k_gather1(
        const unsigned int* __restrict__ xs, const int* __restrict__ slot,
        const int* __restrict__ cnt, unsigned int* __restrict__ agg) {
    int n = blockIdx.x * 4 + (threadIdx.x >> 6);   // 4 waves / block, 1 node / wave
    int c = threadIdx.x & 63;                      // uint column (2 bf16)
    if (n >= NN) return;
    int deg = cnt[n]; if (deg > SLOT) deg = SLOT;
    float dn = rsqrtf((float)deg + 1.0f);
    const int* sl = slot + n * SLOT;
    unsigned a = xs[(size_t)n * 64 + c];
    float s0 = bflo(a), s1 = bfhi(a);
    int j = 0;
    for (; j + 8 <= deg; j += 8) {
        int i0 = sl[j],     i1 = sl[j + 1], i2 = sl[j + 2], i3 = sl[j + 3];
        int i4 = sl[j + 4], i5 = sl[j + 5], i6 = sl[j + 6], i7 = sl[j + 7];
        unsigned v0 = xs[(size_t)i0 * 64 + c];
        unsigned v1 = xs[(size_t)i1 * 64 + c];
        unsigned v2 = xs[(size_t)i2 * 64 + c];
        unsigned v3 = xs[(size_t)i3 * 64 + c];
        unsigned v4 = xs[(size_t)i4 * 64 + c];
        unsigned v5 = xs[(size_t)i5 * 64 + c];
        unsigned v6 = xs[(size_t)i6 * 64 + c];
        unsigned v7 = xs[(size_t)i7 * 64 + c];
        s0 += bflo(v0) + bflo(v1) + bflo(v2) + bflo(v3)
            + bflo(v4) + bflo(v5) + bflo(v6) + bflo(v7);
        s1 += bfhi(v0) + bfhi(v1) + bfhi(v2) + bfhi(v3)
            + bfhi(v4) + bfhi(v5) + bfhi(v6) + bfhi(v7);
    }
    for (; j + 4 <= deg; j += 4) {
        int i0 = sl[j], i1 = sl[j + 1], i2 = sl[j + 2], i3 = sl[j + 3];
        unsigned v0 = xs[(size_t)i0 * 64 + c];
        unsigned v1 = xs[(size_t)i1 * 64 + c];
        unsigned v2 = xs[(size_t)i2 * 64 + c];
        unsigned v3 = xs[(size_t)i3 * 64 + c];
        s0 += bflo(v0) + bflo(v1) + bflo(v2) + bflo(v3);
        s1 += bfhi(v0) + bfhi(v1) + bfhi(v2) + bfhi(v3);
    }
    for (; j < deg; ++j) {
        unsigned v = xs[(size_t)sl[j] * 64 + c];
        s0 += bflo(v); s1 += bfhi(v);
    }
    agg[(size_t)n * 64 + c] =
        (unsigned)f2bf(dn * s0) | ((unsigned)f2bf(dn * s1) << 16);
}

// ========= k_fused: t2s = rowscale( relu(A@W1t^T + b1) @ W2t^T ) =============
// Per block: 32 rows. Phase 1 -> h1 tile in LDS (32x512 bf16, row-XOR swizzle);
// Phase 2 -> 32x256 output, W2t dbuf-staged. A-frags live in registers.
// LDS = 2x16KB staging + 32KB H = 64KB -> 2 blocks/CU. Weights are L2-hot.
__global__ __launch_bounds__(256) void k_fused(
        const unsigned short* __restrict__ A,    // agg1 [M,128]
        const unsigned short* __restrict__ W1t,  // [512,128]
        const unsigned short* __restrict__ W2t,  // [256,512]
        const float* __restrict__ b1,
        const int* __restrict__ cnt,
        unsigned short* __restrict__ C,          // t2s [M,256]
        int M)
{
    __shared__ unsigned short Bs[2][64 * 128];   // 2 x 16 KB staging buffers
    __shared__ unsigned short H[32 * 512];       // 32 KB h1 tile

    const int tid = threadIdx.x;
    const int wv = tid >> 6, ln = tid & 63;
    const int wy = wv >> 1, wx = wv & 1;
    const int lane15 = ln & 15, quad = ln >> 4;
    const int m0 = blockIdx.x * 32;

    // A fragments in registers: wave half wy owns rows m0+wy*16..+15, K=128
    int arow = m0 + wy * 16 + lane15; if (arow > M - 1) arow = M - 1;
    const short8* ap = (const short8*)(A + (size_t)arow * 128);
    short8 af4[4];
#pragma unroll
    for (int kk = 0; kk < 4; ++kk) af4[kk] = ap[kk * 4 + quad];

    // prologue: stage phase-1 iter 0 (W1t rows 0..63) into Bs[0]
#pragma unroll
    for (int i = 0; i < 4; ++i) {
        int c = i * 256 + tid;
        int n = c >> 4, q = c & 15;
        int gq = q ^ (n & 15);
        __builtin_amdgcn_global_load_lds(
            (const __attribute__((address_space(1))) void*)(W1t + (size_t)n * 128 + gq * 8),
            (__attribute__((address_space(3))) void*)(&Bs[0][0] + (i * 4 + wv) * 512), 16, 0, 0);
    }

    // ---------------- phase 1: H = relu(A @ W1t^T + b1) ----------------
    for (int it = 0; it < 8; ++it) {
        __syncthreads();                         // Bs[it&1] staged (vmcnt drained)
        if (it < 7) {                            // stage next 64 W1t rows
            int n0n = (it + 1) * 64;
#pragma unroll
            for (int i = 0; i < 4; ++i) {
                int c = i * 256 + tid;
                int n = c >> 4, q = c & 15;
                int gq = q ^ (n & 15);
                __builtin_amdgcn_global_load_lds(
                    (const __attribute__((address_space(1))) void*)(W1t + (size_t)(n0n + n) * 128 + gq * 8),
                    (__attribute__((address_space(3))) void*)(&Bs[(it + 1) & 1][0] + (i * 4 + wv) * 512), 16, 0, 0);
            }
        } else {                                 // stage phase-2 ks=0 into Bs[0]
#pragma unroll
            for (int i = 0; i < 4; ++i) {
                int c = i * 256 + tid;
                int n = c >> 2, q = c & 3;
                int gq = q ^ ((n >> 1) & 3);
                __builtin_amdgcn_global_load_lds(
                    (const __attribute__((address_space(1))) void*)(W2t + (size_t)n * 512 + gq * 8),
                    (__attribute__((address_space(3))) void*)(&Bs[0][0] + (i * 4 + wv) * 512), 16, 0, 0);
            }
        }
        const unsigned short* B = &Bs[it & 1][0];
        f32x4 acc[2];
        acc[0] = (f32x4)0.0f; acc[1] = (f32x4)0.0f;
#pragma unroll
        for (int kk = 0; kk < 4; ++kk) {
            short8 bf[2];
#pragma unroll
            for (int f = 0; f < 2; ++f) {
                int nB = wx * 32 + f * 16 + lane15;
                int sB = (kk * 4 + quad) ^ (nB & 15);
                bf[f] = *(const short8*)(B + nB * 128 + sB * 8);
            }
#pragma unroll
            for (int f = 0; f < 2; ++f)
                acc[f] = __builtin_amdgcn_mfma_f32_16x16x32_bf16(
                    af4[kk], bf[f], acc[f], 0, 0, 0);
        }
        // epilogue: bias + relu -> H, byte addr ^= (row&7)<<4 (bank spread)
#pragma unroll
        for (int f = 0; f < 2; ++f) {
            int col = it * 64 + wx * 32 + f * 16 + lane15;
            float bia = b1[col];
#pragma unroll
            for (int r = 0; r < 4; ++r) {
                int lrow = wy * 16 + quad * 4 + r;
                unsigned byteoff = (unsigned)(lrow * 1024 + col * 2)
                                 ^ (unsigned)((lrow & 7) << 4);
                *(unsigned short*)((char*)H + byteoff) =
                    f2bf(fmaxf(acc[f][r] + bia, 0.0f));
            }
        }
    }

    // ---------------- phase 2: C = rowscale( H @ W2t^T ) ----------------
    const unsigned hbase = (unsigned)((wy * 16 + lane15) * 1024);
    const unsigned hxor  = (unsigned)(((wy * 16 + lane15) & 7) << 4);

    f32x4 acc2[8];
#pragma unroll
    for (int f = 0; f < 8; ++f) acc2[f] = (f32x4)0.0f;

    for (int ks = 0; ks < 16; ++ks) {
        __syncthreads();                         // Bs[ks&1] staged; H visible (ks=0)
        if (ks < 15) {
            int ko = (ks + 1) << 5;
#pragma unroll
            for (int i = 0; i < 4; ++i) {
                int c = i * 256 + tid;
                int n = c >> 2, q = c & 3;
                int gq = q ^ ((n >> 1) & 3);
                __builtin_amdgcn_global_load_lds(
                    (const __attribute__((address_space(1))) void*)(W2t + (size_t)n * 512 + ko + gq * 8),
                    (__attribute__((address_space(3))) void*)(&Bs[(ks + 1) & 1][0] + (i * 4 + wv) * 512), 16, 0, 0);
            }
        }
        const unsigned short* B = &Bs[ks & 1][0];
        short8 afv = *(const short8*)((const char*)H
                        + ((hbase + (unsigned)(ks * 64 + quad * 16)) ^ hxor));
        short8 bf[8];
#pragma unroll
        for (int f = 0; f < 8; ++f) {
            int nB = wx * 128 + f * 16 + lane15;
            int sB = quad ^ ((nB >> 1) & 3);
            bf[f] = *(const short8*)(B + nB * 32 + sB * 8);
        }
#pragma unroll
        for (int f = 0; f < 8; ++f)
            acc2[f] = __builtin_amdgcn_mfma_f32_16x16x32_bf16(
                afv, bf[f], acc2[f], 0, 0, 0);
    }

    float rs[4];
#pragma unroll
    for (int r = 0; r < 4; ++r) {
        int row = m0 + wy * 16 + quad * 4 + r; if (row > M - 1) row = M - 1;
        rs[r] = rsqrtf((float)cnt[row] + 1.0f);
    }
#pragma unroll
    for (int f = 0; f < 8; ++f) {
        int col = wx * 128 + f * 16 + lane15;
        f32x4 v = acc2[f];
#pragma unroll
        for (int r = 0; r < 4; ++r) {
            int row = m0 + wy * 16 + quad * 4 + r;
            if (row < M)
                C[(size_t)row * 256 + col] = f2bf(v[r] * rs[r]);
        }
    }
}

// ========= gather2: out[n] = relu( dn*( t2s[n] + sum t2s[s] ) + b2 ) (r0) ====
__global__ __launch_bounds__(256) void k_gather2(
        const ushort4* __restrict__ t4, const int* __restrict__ slot,
        const int* __restrict__ cnt, const float* __restrict__ b2,
        float* __restrict__ out) {
    int n = blockIdx.x * 4 + (threadIdx.x >> 6);
    int c = threadIdx.x & 63;                     // 4 bf16 per lane over 256 cols
    if (n >= NN) return;
    int deg = cnt[n]; if (deg > SLOT) deg = SLOT;
    float dn = rsqrtf((float)deg + 1.0f);
    const int* sl = slot + n * SLOT;
    ushort4 a = t4[(size_t)n * 64 + c];
    float sx = bf2f(a.x), sy = bf2f(a.y), sz = bf2f(a.z), sw = bf2f(a.w);
    int j = 0;
    for (; j + 8 <= deg; j += 8) {
        int i0 = sl[j],     i1 = sl[j + 1], i2 = sl[j + 2], i3 = sl[j + 3];
        int i4 = sl[j + 4], i5 = sl[j + 5], i6 = sl[j + 6], i7 = sl[j + 7];
        ushort4 v0 = t4[(size_t)i0 * 64 + c];
        ushort4 v1 = t4[(size_t)i1 * 64 + c];
        ushort4 v2 = t4[(size_t)i2 * 64 + c];
        ushort4 v3 = t4[(size_t)i3 * 64 + c];
        ushort4 v4 = t4[(size_t)i4 * 64 + c];
        ushort4 v5 = t4[(size_t)i5 * 64 + c];
        ushort4 v6 = t4[(size_t)i6 * 64 + c];
        ushort4 v7 = t4[(size_t)i7 * 64 + c];
        sx += bf2f(v0.x) + bf2f(v1.x) + bf2f(v2.x) + bf2f(v3.x)
            + bf2f(v4.x) + bf2f(v5.x) + bf2f(v6.x) + bf2f(v7.x);
        sy += bf2f(v0.y) + bf2f(v1.y) + bf2f(v2.y) + bf2f(v3.y)
            + bf2f(v4.y) + bf2f(v5.y) + bf2f(v6.y) + bf2f(v7.y);
        sz += bf2f(v0.z) + bf2f(v1.z) + bf2f(v2.z) + bf2f(v3.z)
            + bf2f(v4.z) + bf2f(v5.z) + bf2f(v6.z) + bf2f(v7.z);
        sw += bf2f(v0.w) + bf2f(v1.w) + bf2f(v2.w) + bf2f(v3.w)
            + bf2f(v4.w) + bf2f(v5.w) + bf2f(v6.w) + bf2f(v7.w);
    }
    for (; j + 4 <= deg; j += 4) {
        int i0 = sl[j], i1 = sl[j + 1], i2 = sl[j + 2], i3 = sl[j + 3];
        ushort4 v0 = t4[(size_t)i0 * 64 + c];
        ushort4 v1 = t4[(size_t)i1 * 64 + c];
        ushort4 v2 = t4[(size_t)i2 * 64 + c];
        ushort4 v3 = t4[(size_t)i3 * 64 + c];
        sx += bf2f(v0.x) + bf2f(v1.x) + bf2f(v2.x) + bf2f(v3.x);
        sy += bf2f(v0.y) + bf2f(v1.y) + bf2f(v2.y) + bf2f(v3.y);
        sz += bf2f(v0.z) + bf2f(v1.z) + bf2f(v2.z) + bf2f(v3.z);
        sw += bf2f(v0.w) + bf2f(v1.w) + bf2f(v2.w) + bf2f(v3.w);
    }
    for (; j < deg; ++j) {
        ushort4 v = t4[(size_t)sl[j] * 64 + c];
        sx += bf2f(v.x); sy += bf2f(v.y); sz += bf2f(v.z); sw += bf2f(v.w);
    }
    int f = c * 4;
    float* o = out + (size_t)n * F2;
    if (f     < F2) o[f]     = fmaxf(dn * sx + b2[f],     0.f);
    if (f + 1 < F2) o[f + 1] = fmaxf(dn * sy + b2[f + 1], 0.f);
    if (f + 2 < F2) o[f + 2] = fmaxf(dn * sz + b2[f + 2], 0.f);
    if (f + 3 < F2) o[f + 3] = fmaxf(dn * sw + b2[f + 3], 0.f);
}

extern "C" void kernel_launch(void* const* d_in, const int* in_sizes, int n_in,
                              void* d_out, int out_size, void* d_ws, size_t ws_size,
                              hipStream_t stream) {
    const float* x  = (const float*)d_in[0];
    const int*   ei = (const int*)d_in[1];     // [2, NE]: first NE = src, next NE = dst
    const float* W1 = (const float*)d_in[2];
    const float* b1 = (const float*)d_in[3];
    const float* W2 = (const float*)d_in[4];
    const float* b2 = (const float*)d_in[5];
    float* out = (float*)d_out;

    // workspace carve (256 B aligned)
    char* p = (char*)d_ws;
    auto carve = [&](size_t bytes) { char* r = p; p += (bytes + 255) & ~(size_t)255; return r; };
    int*            cnt  = (int*)carve(NN * 4);
    int*            slot = (int*)carve((size_t)NN * SLOT * 4);
    unsigned short* xs   = (unsigned short*)carve((size_t)NN * F0 * 2);
    unsigned short* agg1 = (unsigned short*)carve((size_t)NN * F0 * 2);
    unsigned short* t2s  = (unsigned short*)carve((size_t)NN * 256 * 2);
    unsigned short* w1t  = (unsigned short*)carve((size_t)F1 * F0 * 2);
    unsigned short* w2t  = (unsigned short*)carve((size_t)256 * F1 * 2);

    // 1) zero degree counters
    hipMemsetAsync(cnt, 0, NN * sizeof(int), stream);
    // 2) fused hist+bucket CSR build (fixed stride)
    k_build<<<(NE / 4 + 255) / 256, 256, 0, stream>>>(
        (const int4*)ei, (const int4*)(ei + NE), cnt, slot);
    // 3) fused prep: xs = bf16(dinv*x), W1t, W2t
    k_prep<<<6250 + 256 + 512, 256, 0, stream>>>(
        (const float4*)x, cnt, (ushort4*)xs, W1, w1t, W2, w2t);
    // 4) layer 1 aggregate (wave-per-node, high TLP)
    k_gather1<<<(NN + 3) / 4, 256, 0, stream>>>((const unsigned int*)xs, slot, cnt,
                                                (unsigned int*)agg1);
    // 5) fused GEMM1+GEMM2: h1 never leaves LDS
    k_fused<<<MT32, 256, 0, stream>>>(agg1, w1t, w2t, b1, cnt, t2s, NN);
    // 6) gather2 + bias + relu -> out
    k_gather2<<<(NN + 3) / 4, 256, 0, stream>>>((const ushort4*)t2s, slot, cnt, b2, out);
}

// Round 6
// 237.418 us; speedup vs baseline: 1.1018x; 1.0098x over previous
//
#include <hip/hip_runtime.h>

// Problem constants
constexpr int NN  = 50000;   // nodes
constexpr int NE  = 400000;  // edges
constexpr int F0  = 128;     // input features
constexpr int F1  = 512;     // hidden features
constexpr int F2  = 250;     // output features
constexpr int MT64 = 782;    // M tiles of 64 (782*64 = 50048)
constexpr int SLOT = 64;     // fixed-capacity CSR stride (Poisson(8): P(deg>64)~1e-40)

typedef short  short8 __attribute__((ext_vector_type(8)));
typedef float  f32x4  __attribute__((ext_vector_type(4)));

__device__ inline unsigned short f2bf(float f) {
    union { float f; unsigned u; } v; v.f = f;
    unsigned u = v.u;
    return (unsigned short)((u + 0x7FFFu + ((u >> 16) & 1u)) >> 16);   // RNE
}
__device__ inline float bf2f(unsigned short h) {
    union { unsigned u; float f; } v; v.u = ((unsigned)h) << 16;
    return v.f;
}
__device__ inline float bflo(unsigned u) {
    union { unsigned u; float f; } v; v.u = u << 16; return v.f;
}
__device__ inline float bfhi(unsigned u) {
    union { unsigned u; float f; } v; v.u = u & 0xFFFF0000u; return v.f;
}

// ========= CSR build: fused hist+bucket into fixed-stride slots (r0 form) ====
__global__ void k_build(const int4* __restrict__ src4, const int4* __restrict__ dst4,
                        int* __restrict__ cnt, int* __restrict__ slot) {
    int t = blockIdx.x * 256 + threadIdx.x;        // NE/4
    if (t >= NE / 4) return;
    int4 s = src4[t];
    int4 d = dst4[t];
    int p;
    p = atomicAdd(&cnt[d.x], 1); if (p < SLOT) slot[d.x * SLOT + p] = s.x;
    p = atomicAdd(&cnt[d.y], 1); if (p < SLOT) slot[d.y * SLOT + p] = s.y;
    p = atomicAdd(&cnt[d.z], 1); if (p < SLOT) slot[d.z * SLOT + p] = s.z;
    p = atomicAdd(&cnt[d.w], 1); if (p < SLOT) slot[d.w * SLOT + p] = s.w;
}

// ========= fused prep: xs = bf16(rsqrt(cnt+1)*x), W1t, W2t (r0 form) =========
__global__ __launch_bounds__(256) void k_prep(
        const float4* __restrict__ x4, const int* __restrict__ cnt,
        ushort4* __restrict__ xs,
        const float* __restrict__ W1, unsigned short* __restrict__ w1t,
        const float* __restrict__ W2, unsigned short* __restrict__ w2t) {
    int b = blockIdx.x;
    if (b < 6250) {                                // NN*32 = 1,600,000 float4s
        int t = b * 256 + threadIdx.x;
        float dn = rsqrtf((float)cnt[t >> 5] + 1.0f);
        float4 v = x4[t];
        ushort4 o;
        o.x = f2bf(dn * v.x); o.y = f2bf(dn * v.y);
        o.z = f2bf(dn * v.z); o.w = f2bf(dn * v.w);
        xs[t] = o;
    } else if (b < 6250 + 256) {                   // W1 [128,512] -> [512,128]
        int t = (b - 6250) * 256 + threadIdx.x;
        int n = t >> 7, k = t & 127;
        w1t[t] = f2bf(W1[k * F1 + n]);
    } else {                                       // W2 [512,250] -> [256,512], pad
        int t = (b - 6506) * 256 + threadIdx.x;
        int n = t >> 9, k = t & 511;
        w2t[t] = (n < F2) ? f2bf(W2[k * F2 + n]) : (unsigned short)0;
    }
}

// ========= gather1: agg1[n] = bf16( dn * ( xs[n] + sum xs[s] ) ) (r0 form) ===
__global__ __launch_bounds__(256) void k_gather1(
        const unsigned int* __restrict__ xs, const int* __restrict__ slot,
        const int* __restrict__ cnt, unsigned int* __restrict__ agg) {
    int n = blockIdx.x * 4 + (threadIdx.x >> 6);   // 4 waves / block, 1 node / wave
    int c = threadIdx.x & 63;                      // uint column (2 bf16)
    if (n >= NN) return;
    int deg = cnt[n]; if (deg > SLOT) deg = SLOT;
    float dn = rsqrtf((float)deg + 1.0f);
    const int* sl = slot + n * SLOT;
    unsigned a = xs[(size_t)n * 64 + c];
    float s0 = bflo(a), s1 = bfhi(a);
    int j = 0;
    for (; j + 8 <= deg; j += 8) {
        int i0 = sl[j],     i1 = sl[j + 1], i2 = sl[j + 2], i3 = sl[j + 3];
        int i4 = sl[j + 4], i5 = sl[j + 5], i6 = sl[j + 6], i7 = sl[j + 7];
        unsigned v0 = xs[(size_t)i0 * 64 + c];
        unsigned v1 = xs[(size_t)i1 * 64 + c];
        unsigned v2 = xs[(size_t)i2 * 64 + c];
        unsigned v3 = xs[(size_t)i3 * 64 + c];
        unsigned v4 = xs[(size_t)i4 * 64 + c];
        unsigned v5 = xs[(size_t)i5 * 64 + c];
        unsigned v6 = xs[(size_t)i6 * 64 + c];
        unsigned v7 = xs[(size_t)i7 * 64 + c];
        s0 += bflo(v0) + bflo(v1) + bflo(v2) + bflo(v3)
            + bflo(v4) + bflo(v5) + bflo(v6) + bflo(v7);
        s1 += bfhi(v0) + bfhi(v1) + bfhi(v2) + bfhi(v3)
            + bfhi(v4) + bfhi(v5) + bfhi(v6) + bfhi(v7);
    }
    for (; j + 4 <= deg; j += 4) {
        int i0 = sl[j], i1 = sl[j + 1], i2 = sl[j + 2], i3 = sl[j + 3];
        unsigned v0 = xs[(size_t)i0 * 64 + c];
        unsigned v1 = xs[(size_t)i1 * 64 + c];
        unsigned v2 = xs[(size_t)i2 * 64 + c];
        unsigned v3 = xs[(size_t)i3 * 64 + c];
        s0 += bflo(v0) + bflo(v1) + bflo(v2) + bflo(v3);
        s1 += bfhi(v0) + bfhi(v1) + bfhi(v2) + bfhi(v3);
    }
    for (; j < deg; ++j) {
        unsigned v = xs[(size_t)sl[j] * 64 + c];
        s0 += bflo(v); s1 += bfhi(v);
    }
    agg[(size_t)n * 64 + c] =
        (unsigned)f2bf(dn * s0) | ((unsigned)f2bf(dn * s1) << 16);
}

// ========= k_fused v2: t2s = rowscale( relu(A@W1t^T + b1) @ W2t^T ) ==========
// 64 rows/block, 4 waves column-split (no duplicated weight reads).
// Weights global->reg (L2-hot, shared across all blocks). H in LDS (64 KB,
// row-XOR swizzle). ONE barrier total. 384 MFMA/wave.
__global__ __launch_bounds__(256) void k_fused(
        const unsigned short* __restrict__ A,    // agg1 [M,128]
        const unsigned short* __restrict__ W1t,  // [512,128]
        const unsigned short* __restrict__ W2t,  // [256,512]
        const float* __restrict__ b1,
        const int* __restrict__ cnt,
        unsigned short* __restrict__ C,          // t2s [M,256]
        int M)
{
    __shared__ unsigned short H[64 * 512];       // 64 KB h1 tile

    const int tid = threadIdx.x;
    const int wv = tid >> 6, ln = tid & 63;
    const int lane15 = ln & 15, quad = ln >> 4;
    const int m0 = blockIdx.x * 64;

    // A fragments: row = rf*16 + lane15, k = kk*32 + quad*8  (64 VGPR)
    short8 af[4][4];
#pragma unroll
    for (int rf = 0; rf < 4; ++rf) {
        int arow = m0 + rf * 16 + lane15; if (arow > M - 1) arow = M - 1;
        const short8* ap = (const short8*)(A + (size_t)arow * 128);
#pragma unroll
        for (int kk = 0; kk < 4; ++kk)
            af[rf][kk] = ap[kk * 4 + quad];
    }

    // ---------------- phase 1: H = relu(A @ W1t^T + b1) ----------------
    // wave wv covers output cols wv*128 .. wv*128+127 (8 frags of 16)
#pragma unroll 2
    for (int f = 0; f < 8; ++f) {
        const int nB = wv * 128 + f * 16 + lane15;     // W1t row == h col
        const short8* bp = (const short8*)(W1t + (size_t)nB * 128);
        short8 bf[4];
#pragma unroll
        for (int kk = 0; kk < 4; ++kk) bf[kk] = bp[kk * 4 + quad];
        f32x4 acc[4];
#pragma unroll
        for (int rf = 0; rf < 4; ++rf) acc[rf] = (f32x4)0.0f;
#pragma unroll
        for (int kk = 0; kk < 4; ++kk)
#pragma unroll
            for (int rf = 0; rf < 4; ++rf)
                acc[rf] = __builtin_amdgcn_mfma_f32_16x16x32_bf16(
                    af[rf][kk], bf[kk], acc[rf], 0, 0, 0);
        const float bia = b1[nB];
#pragma unroll
        for (int rf = 0; rf < 4; ++rf)
#pragma unroll
            for (int r = 0; r < 4; ++r) {
                int lrow = rf * 16 + quad * 4 + r;
                unsigned byteoff = (unsigned)(lrow * 1024 + nB * 2)
                                 ^ (unsigned)((lrow & 7) << 4);
                *(unsigned short*)((char*)H + byteoff) =
                    f2bf(fmaxf(acc[rf][r] + bia, 0.0f));
            }
    }

    __syncthreads();                               // the only barrier

    // ---------------- phase 2: C = rowscale( H @ W2t^T ) ----------------
    // wave wv covers output cols wv*64 .. wv*64+63 (4 frags of 16)
    f32x4 acc2[4][4];
#pragma unroll
    for (int rf = 0; rf < 4; ++rf)
#pragma unroll
        for (int cf = 0; cf < 4; ++cf)
            acc2[rf][cf] = (f32x4)0.0f;

#pragma unroll 2
    for (int ks = 0; ks < 16; ++ks) {
        short8 bf[4];
#pragma unroll
        for (int cf = 0; cf < 4; ++cf) {
            int nB = wv * 64 + cf * 16 + lane15;       // W2t row == out col
            bf[cf] = *(const short8*)(W2t + (size_t)nB * 512 + ks * 32 + quad * 8);
        }
        short8 hf[4];
#pragma unroll
        for (int rf = 0; rf < 4; ++rf) {
            int lrow = rf * 16 + lane15;
            unsigned byteoff = (unsigned)(lrow * 1024 + (ks * 32 + quad * 8) * 2)
                             ^ (unsigned)((lrow & 7) << 4);
            hf[rf] = *(const short8*)((const char*)H + byteoff);
        }
#pragma unroll
        for (int rf = 0; rf < 4; ++rf)
#pragma unroll
            for (int cf = 0; cf < 4; ++cf)
                acc2[rf][cf] = __builtin_amdgcn_mfma_f32_16x16x32_bf16(
                    hf[rf], bf[cf], acc2[rf][cf], 0, 0, 0);
    }

#pragma unroll
    for (int rf = 0; rf < 4; ++rf) {
        float rs[4];
#pragma unroll
        for (int r = 0; r < 4; ++r) {
            int row = m0 + rf * 16 + quad * 4 + r; if (row > M - 1) row = M - 1;
            rs[r] = rsqrtf((float)cnt[row] + 1.0f);
        }
#pragma unroll
        for (int cf = 0; cf < 4; ++cf) {
            int col = wv * 64 + cf * 16 + lane15;
            f32x4 v = acc2[rf][cf];
#pragma unroll
            for (int r = 0; r < 4; ++r) {
                int row = m0 + rf * 16 + quad * 4 + r;
                if (row < M)
                    C[(size_t)row * 256 + col] = f2bf(v[r] * rs[r]);
            }
        }
    }
}

// ========= gather2: out[n] = relu( dn*( t2s[n] + sum t2s[s] ) + b2 ) (r0) ====
__global__ __launch_bounds__(256) void k_gather2(
        const ushort4* __restrict__ t4, const int* __restrict__ slot,
        const int* __restrict__ cnt, const float* __restrict__ b2,
        float* __restrict__ out) {
    int n = blockIdx.x * 4 + (threadIdx.x >> 6);
    int c = threadIdx.x & 63;                     // 4 bf16 per lane over 256 cols
    if (n >= NN) return;
    int deg = cnt[n]; if (deg > SLOT) deg = SLOT;
    float dn = rsqrtf((float)deg + 1.0f);
    const int* sl = slot + n * SLOT;
    ushort4 a = t4[(size_t)n * 64 + c];
    float sx = bf2f(a.x), sy = bf2f(a.y), sz = bf2f(a.z), sw = bf2f(a.w);
    int j = 0;
    for (; j + 8 <= deg; j += 8) {
        int i0 = sl[j],     i1 = sl[j + 1], i2 = sl[j + 2], i3 = sl[j + 3];
        int i4 = sl[j + 4], i5 = sl[j + 5], i6 = sl[j + 6], i7 = sl[j + 7];
        ushort4 v0 = t4[(size_t)i0 * 64 + c];
        ushort4 v1 = t4[(size_t)i1 * 64 + c];
        ushort4 v2 = t4[(size_t)i2 * 64 + c];
        ushort4 v3 = t4[(size_t)i3 * 64 + c];
        ushort4 v4 = t4[(size_t)i4 * 64 + c];
        ushort4 v5 = t4[(size_t)i5 * 64 + c];
        ushort4 v6 = t4[(size_t)i6 * 64 + c];
        ushort4 v7 = t4[(size_t)i7 * 64 + c];
        sx += bf2f(v0.x) + bf2f(v1.x) + bf2f(v2.x) + bf2f(v3.x)
            + bf2f(v4.x) + bf2f(v5.x) + bf2f(v6.x) + bf2f(v7.x);
        sy += bf2f(v0.y) + bf2f(v1.y) + bf2f(v2.y) + bf2f(v3.y)
            + bf2f(v4.y) + bf2f(v5.y) + bf2f(v6.y) + bf2f(v7.y);
        sz += bf2f(v0.z) + bf2f(v1.z) + bf2f(v2.z) + bf2f(v3.z)
            + bf2f(v4.z) + bf2f(v5.z) + bf2f(v6.z) + bf2f(v7.z);
        sw += bf2f(v0.w) + bf2f(v1.w) + bf2f(v2.w) + bf2f(v3.w)
            + bf2f(v4.w) + bf2f(v5.w) + bf2f(v6.w) + bf2f(v7.w);
    }
    for (; j + 4 <= deg; j += 4) {
        int i0 = sl[j], i1 = sl[j + 1], i2 = sl[j + 2], i3 = sl[j + 3];
        ushort4 v0 = t4[(size_t)i0 * 64 + c];
        ushort4 v1 = t4[(size_t)i1 * 64 + c];
        ushort4 v2 = t4[(size_t)i2 * 64 + c];
        ushort4 v3 = t4[(size_t)i3 * 64 + c];
        sx += bf2f(v0.x) + bf2f(v1.x) + bf2f(v2.x) + bf2f(v3.x);
        sy += bf2f(v0.y) + bf2f(v1.y) + bf2f(v2.y) + bf2f(v3.y);
        sz += bf2f(v0.z) + bf2f(v1.z) + bf2f(v2.z) + bf2f(v3.z);
        sw += bf2f(v0.w) + bf2f(v1.w) + bf2f(v2.w) + bf2f(v3.w);
    }
    for (; j < deg; ++j) {
        ushort4 v = t4[(size_t)sl[j] * 64 + c];
        sx += bf2f(v.x); sy += bf2f(v.y); sz += bf2f(v.z); sw += bf2f(v.w);
    }
    int f = c * 4;
    float* o = out + (size_t)n * F2;
    if (f     < F2) o[f]     = fmaxf(dn * sx + b2[f],     0.f);
    if (f + 1 < F2) o[f + 1] = fmaxf(dn * sy + b2[f + 1], 0.f);
    if (f + 2 < F2) o[f + 2] = fmaxf(dn * sz + b2[f + 2], 0.f);
    if (f + 3 < F2) o[f + 3] = fmaxf(dn * sw + b2[f + 3], 0.f);
}

extern "C" void kernel_launch(void* const* d_in, const int* in_sizes, int n_in,
                              void* d_out, int out_size, void* d_ws, size_t ws_size,
                              hipStream_t stream) {
    const float* x  = (const float*)d_in[0];
    const int*   ei = (const int*)d_in[1];     // [2, NE]: first NE = src, next NE = dst
    const float* W1 = (const float*)d_in[2];
    const float* b1 = (const float*)d_in[3];
    const float* W2 = (const float*)d_in[4];
    const float* b2 = (const float*)d_in[5];
    float* out = (float*)d_out;

    // workspace carve (256 B aligned)
    char* p = (char*)d_ws;
    auto carve = [&](size_t bytes) { char* r = p; p += (bytes + 255) & ~(size_t)255; return r; };
    int*            cnt  = (int*)carve(NN * 4);
    int*            slot = (int*)carve((size_t)NN * SLOT * 4);
    unsigned short* xs   = (unsigned short*)carve((size_t)NN * F0 * 2);
    unsigned short* agg1 = (unsigned short*)carve((size_t)NN * F0 * 2);
    unsigned short* t2s  = (unsigned short*)carve((size_t)NN * 256 * 2);
    unsigned short* w1t  = (unsigned short*)carve((size_t)F1 * F0 * 2);
    unsigned short* w2t  = (unsigned short*)carve((size_t)256 * F1 * 2);

    // 1) zero degree counters
    hipMemsetAsync(cnt, 0, NN * sizeof(int), stream);
    // 2) fused hist+bucket CSR build (fixed stride)
    k_build<<<(NE / 4 + 255) / 256, 256, 0, stream>>>(
        (const int4*)ei, (const int4*)(ei + NE), cnt, slot);
    // 3) fused prep: xs = bf16(dinv*x), W1t, W2t
    k_prep<<<6250 + 256 + 512, 256, 0, stream>>>(
        (const float4*)x, cnt, (ushort4*)xs, W1, w1t, W2, w2t);
    // 4) layer 1 aggregate (wave-per-node, high TLP)
    k_gather1<<<(NN + 3) / 4, 256, 0, stream>>>((const unsigned int*)xs, slot, cnt,
                                                (unsigned int*)agg1);
    // 5) fused GEMM1+GEMM2 v2: weights global->reg, one barrier
    k_fused<<<MT64, 256, 0, stream>>>(agg1, w1t, w2t, b1, cnt, t2s, NN);
    // 6) gather2 + bias + relu -> out
    k_gather2<<<(NN + 3) / 4, 256, 0, stream>>>((const ushort4*)t2s, slot, cnt, b2, out);
}